// Round 12
// baseline (253.817 us; speedup 1.0000x reference)
//
#include <hip/hip_runtime.h>

#define BB 8
#define CC 128
#define NN 4096   // H*W = 64*64

typedef __bf16 bf16x8_t __attribute__((ext_vector_type(8)));
typedef unsigned short u16x8 __attribute__((ext_vector_type(8)));
typedef float f32x4 __attribute__((ext_vector_type(4)));
typedef unsigned int u32x4 __attribute__((ext_vector_type(4)));
typedef __attribute__((address_space(1))) const unsigned int gu32;
typedef __attribute__((address_space(3))) unsigned int lu32;

#define KSCALE 0.12753262456033348f   // (1/sqrt(128)) * log2(e)

__device__ __forceinline__ unsigned short f2bf(float f) {
  unsigned int u = __builtin_bit_cast(unsigned int, f);
  u += 0x7fffu + ((u >> 16) & 1u);          // RNE
  return (unsigned short)(u >> 16);
}

__device__ __forceinline__ unsigned int cvt_pk_bf16(float lo, float hi) {
  unsigned int r;
  asm("v_cvt_pk_bf16_f32 %0, %1, %2" : "=v"(r) : "v"(lo), "v"(hi));
  return r;
}

__device__ __forceinline__ f32x4 mfma16(u16x8 a, u16x8 b, f32x4 c) {
  return __builtin_amdgcn_mfma_f32_16x16x32_bf16(
      __builtin_bit_cast(bf16x8_t, a), __builtin_bit_cast(bf16x8_t, b), c, 0, 0, 0);
}

// ---------------------------------------------------------------------------
// Kernel 0: prep.  Blocks 0..63: Wq*KSCALE, Wv -> bf16.  Block 64: csk[c]=sum_o Wk[o][c]
// ---------------------------------------------------------------------------
__global__ void prep(const float* __restrict__ Wq, const float* __restrict__ Wv,
                     const float* __restrict__ Wk,
                     unsigned short* __restrict__ Qwb, unsigned short* __restrict__ Vwb,
                     float* __restrict__ csk) {
  if (blockIdx.x < 64) {
    const int i = blockIdx.x * 256 + threadIdx.x;
    Qwb[i] = f2bf(Wq[i] * KSCALE);
    Vwb[i] = f2bf(Wv[i]);
  } else if (threadIdx.x < CC) {
    const int c = threadIdx.x;
    float s = 0.f;
    for (int o = 0; o < CC; ++o) s += Wk[(size_t)o * CC + c];
    csk[c] = s;
  }
}

// ---------------------------------------------------------------------------
// Kernel 1: QKV projection (proven).
// ---------------------------------------------------------------------------
__global__ __launch_bounds__(256, 2) void qkv_proj(
    const float* __restrict__ x,
    const unsigned short* __restrict__ Qwb, const float* __restrict__ bq,
    const float* __restrict__ csk, const float* __restrict__ bk,
    const unsigned short* __restrict__ Vwb, const float* __restrict__ bv,
    unsigned short* __restrict__ Q,
    unsigned short* __restrict__ K,
    unsigned short* __restrict__ V)
{
  const int b  = blockIdx.x & 7;
  const int n0 = (blockIdx.x >> 3) << 6;
  const int t  = threadIdx.x;
  const int lane = t & 63;
  const int w  = t >> 6;
  const int lq = lane & 15;
  const int g  = lane >> 4;

  __shared__ unsigned short xs[64][136];
  __shared__ unsigned short ks[64][136];
  __shared__ unsigned short vs[128][72];

  {
    const int n = t & 63;
    const float* xp = x + (size_t)b * (CC * NN) + n0 + n;
    for (int c = t >> 6; c < CC; c += 4) {
      const float xv = xp[(size_t)c * NN];
      xs[n][c] = f2bf(xv);
      ks[n][c] = f2bf(xv * csk[c] + bk[c]);
    }
  }
  __syncthreads();

  u16x8 a[4];
  {
    const unsigned short* ap = &xs[w * 16 + lq][g * 8];
    for (int ksl = 0; ksl < 4; ++ksl) a[ksl] = *(const u16x8*)(ap + ksl * 32);
  }

  for (int ot = 0; ot < 8; ++ot) {
    f32x4 aq = {0.f,0.f,0.f,0.f}, av = {0.f,0.f,0.f,0.f};
    const int o = ot * 16 + lq;
    const unsigned short* wq = Qwb + (size_t)o * CC + g * 8;
    const unsigned short* wv = Vwb + (size_t)o * CC + g * 8;
    for (int ksl = 0; ksl < 4; ++ksl) {
      aq = mfma16(a[ksl], *(const u16x8*)(wq + ksl * 32), aq);
      av = mfma16(a[ksl], *(const u16x8*)(wv + ksl * 32), av);
    }
    const float bqv = bq[o] * KSCALE, bvv = bv[o];
    for (int r = 0; r < 4; ++r) {
      const int nl = w * 16 + g * 4 + r;
      Q[((size_t)b * NN + n0 + nl) * CC + o] = f2bf(aq[r] + bqv);
      vs[o][nl] = f2bf(av[r] + bvv);
    }
  }
  __syncthreads();

  {
    unsigned short* kout = K + ((size_t)b * NN + n0) * CC;
    for (int i = t; i < 64 * 16; i += 256) {
      const int n = i >> 4, oc = (i & 15) * 8;
      *(uint4*)(kout + (size_t)n * CC + oc) = *(const uint4*)&ks[n][oc];
    }
  }
  {
    unsigned short* vout = V + (size_t)b * (CC * NN) + n0;
    for (int i = t; i < 128 * 32; i += 256) {
      const int c  = i >> 5;
      const int np = (i & 31) << 1;
      *(unsigned int*)(vout + (size_t)c * NN + np) = *(const unsigned int*)&vs[c][np];
    }
  }
}

// ---------------------------------------------------------------------------
// Kernel 2: flash attention partials, KV split 2-way (R11 structure: FETCH
// ~12MB, 0 bank conflicts). NEW: cross-tile software pipeline —
//   QK[t+1] (MFMA) issued BEFORE softmax[t] (VALU) so the two pipes overlap
//   within each wave. K triple-buffered (staged 2 ahead, vmcnt(2) steady
//   state), V double-buffered (1 ahead). LDS 80KB = 2 blocks/CU (grid-limited
//   anyway). Score regs ping-pong via manual unroll-by-2 (no v_mov, no
//   runtime-indexed arrays).
// ---------------------------------------------------------------------------
__global__ __launch_bounds__(512, 4) void flash_attn(
    const unsigned short* __restrict__ Q,
    const unsigned short* __restrict__ K,
    const unsigned short* __restrict__ V,
    float* __restrict__ PO0, float* __restrict__ PO1,
    float2* __restrict__ PML)
{
  const int bid = blockIdx.x;
  const int b  = bid & 7;                    // batch -> XCD-local K/V/Q
  const int qb = (bid >> 3) & 31;
  const int sp = bid >> 8;                   // KV half 0/1
  const int kv0 = sp << 11;                  // 2048 keys per half
  const int t  = threadIdx.x;
  const int lane = t & 63;
  const int w  = t >> 6;                     // wave 0..7
  const int lq = lane & 15;
  const int g  = lane >> 4;
  const int q0w = (qb << 7) + (w << 4);      // 16 q-rows per wave

  __shared__ unsigned short KtL[3][64 * 128];   // 48KB: [key][c], swizzled, 3-buf
  __shared__ unsigned short VlL[2][128 * 64];   // 32KB: [ch][64keys permuted], 2-buf

  // Q fragments (B-operand of swapped QK^T): col q = lq
  u16x8 qf[4];
  {
    const unsigned short* qp = Q + ((size_t)b * NN + q0w + lq) * CC + g * 8;
    #pragma unroll
    for (int ksl = 0; ksl < 4; ++ksl) qf[ksl] = *(const u16x8*)(qp + ksl * 32);
  }

  // ---- staging offsets (pre-inverse-swizzled source, linear LDS dest) ----
  const char* kgb = (const char*)(K + (size_t)b * NN * CC);   // 256B key rows
  const char* vgb = (const char*)(V + (size_t)b * CC * NN);   // 8192B channel rows
  int soK[2];
  #pragma unroll
  for (int j = 0; j < 2; ++j) {
    const int p = t * 16 + j * 8192;
    const int row = p >> 8;                    // 0..63
    soK[j] = (p & ~255) | ((p & 255) ^ ((row & 15) << 4));
  }
  int vOff[8];
  #pragma unroll
  for (int n = 0; n < 8; ++n) {
    const int p = t * 4 + n * 2048;
    const int ch = p >> 7;
    const int L = (p & 127) ^ ((ch & 7) << 4);
    const int gb = (L & 7) | (((L >> 4) & 3) << 3) | (((L >> 3) & 1) << 5) | ((L >> 6) << 6);
    vOff[n] = ch * (NN * 2) + gb;
  }
  const int p16 = t * 16;
  const int p4  = t * 4;

  #define STAGE_K(kb_, kv_) do {                                                  \
    const char* kg_ = kgb + ((size_t)(kv_) << 8);                                 \
    _Pragma("unroll")                                                             \
    for (int j_ = 0; j_ < 2; ++j_)                                                \
      __builtin_amdgcn_global_load_lds((gu32*)(kg_ + soK[j_]),                    \
          (lu32*)((char*)KtL + (kb_) * 16384 + p16 + j_ * 8192), 16, 0, 0);       \
  } while (0)
  #define STAGE_V(vb_, kv_) do {                                                  \
    const char* vg_ = vgb + ((size_t)(kv_) << 1);                                 \
    _Pragma("unroll")                                                             \
    for (int n_ = 0; n_ < 8; ++n_)                                                \
      __builtin_amdgcn_global_load_lds((gu32*)(vg_ + vOff[n_]),                   \
          (lu32*)((char*)VlL + (vb_) * 16384 + p4 + n_ * 2048), 4, 0, 0);         \
  } while (0)

  f32x4 oacc[8];
  #pragma unroll
  for (int i = 0; i < 8; ++i) oacc[i] = f32x4{0.f, 0.f, 0.f, 0.f};
  float m_run = -1e30f, l_run = 0.f;

  const int swzK  = lq << 4;                   // K read swizzle: row&15 = lq
  const int swzVl = (lq & 7) << 4;             // V read swizzle: ch&7 = lq&7

  // ---- prologue: tile0 K+V; K tiles 1,2 prefetched; QK[0] -> sA ----
  STAGE_K(0, kv0); STAGE_V(0, kv0);
  asm volatile("s_waitcnt vmcnt(0)" ::: "memory");
  __builtin_amdgcn_s_barrier();
  STAGE_K(1, kv0 + 64); STAGE_K(2, kv0 + 128);

  f32x4 sA[4], sB[4];
  {
    const char* kb = (const char*)KtL + lq * 256;
    #pragma unroll
    for (int kt = 0; kt < 4; ++kt) {
      sA[kt] = f32x4{0.f, 0.f, 0.f, 0.f};
      #pragma unroll
      for (int ksl = 0; ksl < 4; ++ksl) {
        u16x8 kf = *(const u16x8*)(kb + kt * 4096 + ((ksl * 64 + g * 16) ^ swzK));
        sA[kt] = mfma16(kf, qf[ksl], sA[kt]);
      }
    }
  }
  int krd = 1;     // K buffer holding tile T+1
  int kwr = 0;     // K buffer to receive tile T+3

  // ---- pipelined main loop: finish tile T, compute QK of tile T+1 ----
  #define BODY(T, SC, SN) do {                                                    \
    if ((T) < 30) { asm volatile("s_waitcnt vmcnt(2)" ::: "memory"); }            \
    else          { asm volatile("s_waitcnt vmcnt(0)" ::: "memory"); }            \
    __builtin_amdgcn_s_barrier();                                                 \
    /* QK[T+1] (MFMA) — independent of softmax below, pipes overlap */            \
    if ((T) < 31) {                                                               \
      const char* kb_ = (const char*)KtL + krd * 16384 + lq * 256;                \
      __builtin_amdgcn_s_setprio(1);                                              \
      _Pragma("unroll")                                                           \
      for (int kt = 0; kt < 4; ++kt) {                                            \
        SN[kt] = f32x4{0.f, 0.f, 0.f, 0.f};                                       \
        _Pragma("unroll")                                                         \
        for (int ksl = 0; ksl < 4; ++ksl) {                                       \
          u16x8 kf = *(const u16x8*)(kb_ + kt * 4096 + ((ksl * 64 + g * 16) ^ swzK)); \
          SN[kt] = mfma16(kf, qf[ksl], SN[kt]);                                   \
        }                                                                         \
      }                                                                           \
      __builtin_amdgcn_s_setprio(0);                                              \
    }                                                                             \
    /* online softmax of tile T (VALU) */                                         \
    float pm_ = fmaxf(fmaxf(SC[0][0], SC[0][1]), fmaxf(SC[0][2], SC[0][3]));      \
    _Pragma("unroll")                                                             \
    for (int kt = 1; kt < 4; ++kt)                                                \
      pm_ = fmaxf(pm_, fmaxf(fmaxf(SC[kt][0], SC[kt][1]), fmaxf(SC[kt][2], SC[kt][3]))); \
    pm_ = fmaxf(pm_, __shfl_xor(pm_, 16));                                        \
    pm_ = fmaxf(pm_, __shfl_xor(pm_, 32));                                        \
    if (!__all(pm_ - m_run <= 8.0f)) {                                            \
      const float m_new_ = fmaxf(m_run, pm_);                                     \
      const float alpha_ = exp2f(m_run - m_new_);                                 \
      l_run *= alpha_;                                                            \
      _Pragma("unroll")                                                           \
      for (int i_ = 0; i_ < 8; ++i_) {                                            \
        oacc[i_][0] *= alpha_; oacc[i_][1] *= alpha_;                             \
        oacc[i_][2] *= alpha_; oacc[i_][3] *= alpha_;                             \
      }                                                                           \
      m_run = m_new_;                                                             \
    }                                                                             \
    float lsum_ = 0.f;                                                            \
    unsigned pkw_[8];                                                             \
    _Pragma("unroll")                                                             \
    for (int kt = 0; kt < 4; ++kt) {                                              \
      const float e0_ = exp2f(SC[kt][0] - m_run), e1_ = exp2f(SC[kt][1] - m_run); \
      const float e2_ = exp2f(SC[kt][2] - m_run), e3_ = exp2f(SC[kt][3] - m_run); \
      lsum_ += (e0_ + e1_) + (e2_ + e3_);                                         \
      pkw_[kt * 2 + 0] = cvt_pk_bf16(e0_, e1_);                                   \
      pkw_[kt * 2 + 1] = cvt_pk_bf16(e2_, e3_);                                   \
    }                                                                             \
    lsum_ += __shfl_xor(lsum_, 16);                                               \
    lsum_ += __shfl_xor(lsum_, 32);                                               \
    l_run += lsum_;                                                               \
    u32x4 pw0_ = {pkw_[0], pkw_[1], pkw_[2], pkw_[3]};                            \
    u32x4 pw1_ = {pkw_[4], pkw_[5], pkw_[6], pkw_[7]};                            \
    const u16x8 pf0_ = __builtin_bit_cast(u16x8, pw0_);                           \
    const u16x8 pf1_ = __builtin_bit_cast(u16x8, pw1_);                           \
    /* PV of tile T */                                                            \
    const char* vbb_ = (const char*)VlL + ((T) & 1) * 16384;                      \
    __builtin_amdgcn_s_setprio(1);                                                \
    _Pragma("unroll")                                                             \
    for (int dt = 0; dt < 8; ++dt) {                                              \
      const char* vp_ = vbb_ + (dt * 16 + lq) * 128;                              \
      u16x8 vf0_ = *(const u16x8*)(vp_ + ((g * 16) ^ swzVl));                     \
      oacc[dt] = mfma16(vf0_, pf0_, oacc[dt]);                                    \
      u16x8 vf1_ = *(const u16x8*)(vp_ + ((64 + g * 16) ^ swzVl));                \
      oacc[dt] = mfma16(vf1_, pf1_, oacc[dt]);                                    \
    }                                                                             \
    __builtin_amdgcn_s_setprio(0);                                                \
    asm volatile("s_waitcnt lgkmcnt(0)" ::: "memory");                            \
    __builtin_amdgcn_s_barrier();                                                 \
    if ((T) < 31) STAGE_V(((T) + 1) & 1, kv0 + ((T) + 1) * 64);                   \
    if ((T) < 29) STAGE_K(kwr, kv0 + ((T) + 3) * 64);                             \
    krd = (krd == 2) ? 0 : krd + 1;                                               \
    kwr = (kwr == 2) ? 0 : kwr + 1;                                               \
  } while (0)

  for (int ti = 0; ti < 16; ++ti) {
    BODY(2 * ti,     sA, sB);
    BODY(2 * ti + 1, sB, sA);
  }
  #undef BODY
  #undef STAGE_K
  #undef STAGE_V

  // ---- epilogue: unnormalized fp32 partials, channel-major + (m,l) ----
  float* po = (sp ? PO1 : PO0) + (size_t)b * (CC * NN);
  const int n = q0w + lq;
  #pragma unroll
  for (int dt = 0; dt < 8; ++dt) {
    #pragma unroll
    for (int r = 0; r < 4; ++r) {
      const int c = dt * 16 + g * 4 + r;
      po[(size_t)c * NN + n] = oacc[dt][r];
    }
  }
  if (g == 0) PML[((size_t)sp * BB + b) * NN + n] = float2{m_run, l_run};
}

// ---------------------------------------------------------------------------
// Kernel 3: combine two KV-half partials + residual (proven).
// ---------------------------------------------------------------------------
__global__ __launch_bounds__(256) void combine(
    const float* __restrict__ x, const float* __restrict__ PO1,
    const float2* __restrict__ PML, float* __restrict__ out)
{
  const size_t base = ((size_t)blockIdx.x * 256 + threadIdx.x) * 4;
  const int n = (int)(base & 4095);
  const int rest = (int)(base >> 12);
  const int b = rest >> 7;                    // rest = b*128 + c
  const float2* ml0 = PML + (size_t)b * NN + n;
  const float2* ml1 = PML + (size_t)(BB + b) * NN + n;
  float4 o0 = *(const float4*)(out + base);   // half 0 stored in d_out
  float4 o1 = *(const float4*)(PO1 + base);
  float4 xv = *(const float4*)(x + base);
  float4 r;
  #pragma unroll
  for (int i = 0; i < 4; ++i) {
    const float m0 = ml0[i].x, l0 = ml0[i].y;
    const float m1 = ml1[i].x, l1 = ml1[i].y;
    const float M = fmaxf(m0, m1);
    const float w0 = exp2f(m0 - M), w1 = exp2f(m1 - M);
    const float num = w0 * ((const float*)&o0)[i] + w1 * ((const float*)&o1)[i];
    const float den = w0 * l0 + w1 * l1;
    ((float*)&r)[i] = ((const float*)&xv)[i] + num / den;
  }
  *(float4*)(out + base) = r;
}

extern "C" void kernel_launch(void* const* d_in, const int* in_sizes, int n_in,
                              void* d_out, int out_size, void* d_ws, size_t ws_size,
                              hipStream_t stream) {
  (void)in_sizes; (void)n_in; (void)out_size; (void)ws_size;
  const float* x  = (const float*)d_in[0];
  const float* Wq = (const float*)d_in[1];
  const float* bq = (const float*)d_in[2];
  const float* Wk = (const float*)d_in[3];
  const float* bk = (const float*)d_in[4];
  const float* Wv = (const float*)d_in[5];
  const float* bv = (const float*)d_in[6];

  unsigned short* Q   = (unsigned short*)d_ws;                  // 8 MB
  unsigned short* K   = Q + (size_t)BB * NN * CC;               // 8 MB
  unsigned short* V   = K + (size_t)BB * NN * CC;               // 8 MB
  float* PO1          = (float*)(V + (size_t)BB * NN * CC);     // 16 MB fp32 partial (half 1)
  float2* PML         = (float2*)(PO1 + (size_t)BB * CC * NN);  // 512 KB stats
  unsigned short* Qwb = (unsigned short*)(PML + (size_t)2 * BB * NN); // 32 KB
  unsigned short* Vwb = Qwb + (size_t)CC * CC;                  // 32 KB
  float* csk = (float*)(Vwb + (size_t)CC * CC);                 // 512 B
  float* out = (float*)d_out;                                   // also fp32 partial 0

  prep<<<dim3(65), dim3(256), 0, stream>>>(Wq, Wv, Wk, Qwb, Vwb, csk);
  qkv_proj<<<dim3(BB * (NN / 64)), dim3(256), 0, stream>>>(x, Qwb, bq, csk, bk, Vwb, bv, Q, K, V);
  flash_attn<<<dim3(BB * 32 * 2), dim3(512), 0, stream>>>(Q, K, V, out, PO1, PML);
  combine<<<dim3((BB * CC * NN) / (256 * 4)), dim3(256), 0, stream>>>(x, PO1, PML, out);
}

// Round 13
// 139.165 us; speedup vs baseline: 1.8239x; 1.8239x over previous
//
#include <hip/hip_runtime.h>

#define BB 8
#define CC 128
#define NN 4096   // H*W = 64*64

typedef __bf16 bf16x8_t __attribute__((ext_vector_type(8)));
typedef unsigned short u16x8 __attribute__((ext_vector_type(8)));
typedef float f32x4 __attribute__((ext_vector_type(4)));
typedef unsigned int u32x4 __attribute__((ext_vector_type(4)));
typedef __attribute__((address_space(1))) const unsigned int gu32;
typedef __attribute__((address_space(3))) unsigned int lu32;

#define KSCALE 0.12753262456033348f   // (1/sqrt(128)) * log2(e)

__device__ __forceinline__ unsigned short f2bf(float f) {
  unsigned int u = __builtin_bit_cast(unsigned int, f);
  u += 0x7fffu + ((u >> 16) & 1u);          // RNE
  return (unsigned short)(u >> 16);
}

__device__ __forceinline__ float bf2f(unsigned short s) {
  unsigned int u = ((unsigned int)s) << 16;
  return __builtin_bit_cast(float, u);
}

__device__ __forceinline__ unsigned int cvt_pk_bf16(float lo, float hi) {
  unsigned int r;
  asm("v_cvt_pk_bf16_f32 %0, %1, %2" : "=v"(r) : "v"(lo), "v"(hi));
  return r;
}

__device__ __forceinline__ f32x4 mfma16(u16x8 a, u16x8 b, f32x4 c) {
  return __builtin_amdgcn_mfma_f32_16x16x32_bf16(
      __builtin_bit_cast(bf16x8_t, a), __builtin_bit_cast(bf16x8_t, b), c, 0, 0, 0);
}

// ---------------------------------------------------------------------------
// Kernel 0: prep.  Blocks 0..63: Wq*KSCALE, Wv -> bf16.  Block 64: csk[c]=sum_o Wk[o][c]
// ---------------------------------------------------------------------------
__global__ void prep(const float* __restrict__ Wq, const float* __restrict__ Wv,
                     const float* __restrict__ Wk,
                     unsigned short* __restrict__ Qwb, unsigned short* __restrict__ Vwb,
                     float* __restrict__ csk) {
  if (blockIdx.x < 64) {
    const int i = blockIdx.x * 256 + threadIdx.x;
    Qwb[i] = f2bf(Wq[i] * KSCALE);
    Vwb[i] = f2bf(Wv[i]);
  } else if (threadIdx.x < CC) {
    const int c = threadIdx.x;
    float s = 0.f;
    for (int o = 0; o < CC; ++o) s += Wk[(size_t)o * CC + c];
    csk[c] = s;
  }
}

// ---------------------------------------------------------------------------
// Kernel 1: QKV projection (proven).
//  Q[b][n][o] = (x.Wq^T + bq) * KSCALE   bf16 pixel-major
//  K[b][n][c] =  x[c][n]*csk[c] + bk[c]  bf16 pixel-major
//  V[b][o][n] =  x.Wv^T + bv             bf16 channel-major
// ---------------------------------------------------------------------------
__global__ __launch_bounds__(256, 2) void qkv_proj(
    const float* __restrict__ x,
    const unsigned short* __restrict__ Qwb, const float* __restrict__ bq,
    const float* __restrict__ csk, const float* __restrict__ bk,
    const unsigned short* __restrict__ Vwb, const float* __restrict__ bv,
    unsigned short* __restrict__ Q,
    unsigned short* __restrict__ K,
    unsigned short* __restrict__ V)
{
  const int b  = blockIdx.x & 7;
  const int n0 = (blockIdx.x >> 3) << 6;
  const int t  = threadIdx.x;
  const int lane = t & 63;
  const int w  = t >> 6;
  const int lq = lane & 15;
  const int g  = lane >> 4;

  __shared__ unsigned short xs[64][136];
  __shared__ unsigned short ks[64][136];
  __shared__ unsigned short vs[128][72];

  {
    const int n = t & 63;
    const float* xp = x + (size_t)b * (CC * NN) + n0 + n;
    for (int c = t >> 6; c < CC; c += 4) {
      const float xv = xp[(size_t)c * NN];
      xs[n][c] = f2bf(xv);
      ks[n][c] = f2bf(xv * csk[c] + bk[c]);
    }
  }
  __syncthreads();

  u16x8 a[4];
  {
    const unsigned short* ap = &xs[w * 16 + lq][g * 8];
    for (int ksl = 0; ksl < 4; ++ksl) a[ksl] = *(const u16x8*)(ap + ksl * 32);
  }

  for (int ot = 0; ot < 8; ++ot) {
    f32x4 aq = {0.f,0.f,0.f,0.f}, av = {0.f,0.f,0.f,0.f};
    const int o = ot * 16 + lq;
    const unsigned short* wq = Qwb + (size_t)o * CC + g * 8;
    const unsigned short* wv = Vwb + (size_t)o * CC + g * 8;
    for (int ksl = 0; ksl < 4; ++ksl) {
      aq = mfma16(a[ksl], *(const u16x8*)(wq + ksl * 32), aq);
      av = mfma16(a[ksl], *(const u16x8*)(wv + ksl * 32), av);
    }
    const float bqv = bq[o] * KSCALE, bvv = bv[o];
    for (int r = 0; r < 4; ++r) {
      const int nl = w * 16 + g * 4 + r;
      Q[((size_t)b * NN + n0 + nl) * CC + o] = f2bf(aq[r] + bqv);
      vs[o][nl] = f2bf(av[r] + bvv);
    }
  }
  __syncthreads();

  {
    unsigned short* kout = K + ((size_t)b * NN + n0) * CC;
    for (int i = t; i < 64 * 16; i += 256) {
      const int n = i >> 4, oc = (i & 15) * 8;
      *(uint4*)(kout + (size_t)n * CC + oc) = *(const uint4*)&ks[n][oc];
    }
  }
  {
    unsigned short* vout = V + (size_t)b * (CC * NN) + n0;
    for (int i = t; i < 128 * 32; i += 256) {
      const int c  = i >> 5;
      const int np = (i & 31) << 1;
      *(unsigned int*)(vout + (size_t)c * NN + np) = *(const unsigned int*)&vs[c][np];
    }
  }
}

// ---------------------------------------------------------------------------
// Kernel 2: flash attention partials, KV split 2-way (R11 structure verbatim:
// FETCH ~12MB, 0 bank conflicts, 2-barrier loop, vmcnt(10)).
// Changes vs R11: (a) bf16 NORMALIZED partials (halves partial write bytes;
// accuracy proven in R6-R8), (b) v_max3-friendly row-max nesting (T17).
// R12's cross-tile pipeline REJECTED (scratch spill + L2 thrash, -100% perf).
// ---------------------------------------------------------------------------
__global__ __launch_bounds__(512, 4) void flash_attn(
    const unsigned short* __restrict__ Q,
    const unsigned short* __restrict__ K,
    const unsigned short* __restrict__ V,
    unsigned short* __restrict__ PO,     // [2][B][C][N] bf16 normalized partials
    float2* __restrict__ PML)            // [2][B][N]
{
  const int bid = blockIdx.x;
  const int b  = bid & 7;                    // batch -> XCD-local K/V/Q
  const int qb = (bid >> 3) & 31;
  const int sp = bid >> 8;                   // KV half 0/1
  const int kv0 = sp << 11;                  // 2048 keys per half
  const int t  = threadIdx.x;
  const int lane = t & 63;
  const int w  = t >> 6;                     // wave 0..7
  const int lq = lane & 15;
  const int g  = lane >> 4;
  const int q0w = (qb << 7) + (w << 4);      // 16 q-rows per wave

  __shared__ unsigned short KtL[2][64 * 128];   // 16KB each: [key][c], swizzled
  __shared__ unsigned short VlL[2][128 * 64];   // 16KB each: [ch][64keys permuted]

  // Q fragments (B-operand of swapped QK^T): col q = lq
  u16x8 qf[4];
  {
    const unsigned short* qp = Q + ((size_t)b * NN + q0w + lq) * CC + g * 8;
    #pragma unroll
    for (int ksl = 0; ksl < 4; ++ksl) qf[ksl] = *(const u16x8*)(qp + ksl * 32);
  }

  // ---- staging offsets (pre-inverse-swizzled source, linear LDS dest) ----
  const char* kgb = (const char*)(K + (size_t)b * NN * CC);   // 256B key rows
  const char* vgb = (const char*)(V + (size_t)b * CC * NN);   // 8192B channel rows
  int soK[2];
  #pragma unroll
  for (int j = 0; j < 2; ++j) {
    const int p = t * 16 + j * 8192;
    const int row = p >> 8;                    // 0..63
    soK[j] = (p & ~255) | ((p & 255) ^ ((row & 15) << 4));
  }
  // V: 8 chunks of 4B per thread. Physical LDS byte p -> channel ch=p>>7,
  // logical L = (p&127) ^ ((ch&7)<<4), global row-byte gb(L):
  //   L bits: b6=kk b5:4=g b3=h b2:1=r b0=parity -> gb = kk<<6|h<<5|g<<3|r<<1|par
  int vOff[8];
  #pragma unroll
  for (int n = 0; n < 8; ++n) {
    const int p = t * 4 + n * 2048;
    const int ch = p >> 7;
    const int L = (p & 127) ^ ((ch & 7) << 4);
    const int gb = (L & 7) | (((L >> 4) & 3) << 3) | (((L >> 3) & 1) << 5) | ((L >> 6) << 6);
    vOff[n] = ch * (NN * 2) + gb;
  }

  #define STAGE(nb, kv) do {                                                      \
    const char* kg_ = kgb + ((size_t)(kv) << 8);                                  \
    const char* vg_ = vgb + ((size_t)(kv) << 1);                                  \
    _Pragma("unroll")                                                             \
    for (int j = 0; j < 2; ++j)                                                   \
      __builtin_amdgcn_global_load_lds((gu32*)(kg_ + soK[j]),                     \
          (lu32*)((char*)KtL + (nb) * 16384 + t * 16 + j * 8192), 16, 0, 0);      \
    _Pragma("unroll")                                                             \
    for (int n = 0; n < 8; ++n)                                                   \
      __builtin_amdgcn_global_load_lds((gu32*)(vg_ + vOff[n]),                    \
          (lu32*)((char*)VlL + (nb) * 16384 + t * 4 + n * 2048), 4, 0, 0);        \
  } while (0)

  f32x4 oacc[8];
  #pragma unroll
  for (int i = 0; i < 8; ++i) oacc[i] = f32x4{0.f, 0.f, 0.f, 0.f};
  float m_run = -1e30f, l_run = 0.f;

  const int swzK  = lq << 4;                   // K read swizzle: row&15 = lq
  const int swzVl = (lq & 7) << 4;             // V read swizzle: ch&7 = lq&7

  STAGE(0, kv0);

  for (int tt = 0; tt < 32; ++tt) {
    const int cur = tt & 1;
    if (tt < 31) {
      STAGE(cur ^ 1, kv0 + (tt + 1) * 64);
      asm volatile("s_waitcnt vmcnt(10)" ::: "memory");  // current tile resident
    } else {
      asm volatile("s_waitcnt vmcnt(0)" ::: "memory");
    }
    __builtin_amdgcn_s_barrier();

    const char* kb  = (const char*)KtL + cur * 16384;
    const char* vbb = (const char*)VlL + cur * 16384;

    // ---- S^T = K . Q^T  (row = key, col = q) ----
    f32x4 s[4];
    #pragma unroll
    for (int kt = 0; kt < 4; ++kt) s[kt] = f32x4{0.f, 0.f, 0.f, 0.f};
    __builtin_amdgcn_s_setprio(1);
    #pragma unroll
    for (int kt = 0; kt < 4; ++kt) {
      const char* kp = kb + (kt * 16 + lq) * 256;
      #pragma unroll
      for (int ksl = 0; ksl < 4; ++ksl) {
        u16x8 kf = *(const u16x8*)(kp + ((ksl * 64 + g * 16) ^ swzK));
        s[kt] = mfma16(kf, qf[ksl], s[kt]);
      }
    }
    __builtin_amdgcn_s_setprio(0);

    // ---- online softmax (per q column; defer-max T13; v_max3 tree T17) ----
    // 16 values via 3-input groups -> v_max3_f32
    float pa = fmaxf(fmaxf(s[0][0], s[0][1]), s[0][2]);
    float pb = fmaxf(fmaxf(s[0][3], s[1][0]), s[1][1]);
    float pc = fmaxf(fmaxf(s[1][2], s[1][3]), s[2][0]);
    float pd = fmaxf(fmaxf(s[2][1], s[2][2]), s[2][3]);
    float pe = fmaxf(fmaxf(s[3][0], s[3][1]), s[3][2]);
    float pm = fmaxf(fmaxf(pa, pb), pc);
    pm = fmaxf(fmaxf(pm, pd), fmaxf(pe, s[3][3]));
    pm = fmaxf(pm, __shfl_xor(pm, 16));
    pm = fmaxf(pm, __shfl_xor(pm, 32));
    if (!__all(pm - m_run <= 8.0f)) {
      const float m_new = fmaxf(m_run, pm);
      const float alpha = exp2f(m_run - m_new);
      l_run *= alpha;
      #pragma unroll
      for (int i = 0; i < 8; ++i) {
        oacc[i][0] *= alpha; oacc[i][1] *= alpha;
        oacc[i][2] *= alpha; oacc[i][3] *= alpha;
      }
      m_run = m_new;
    }
    float lsum = 0.f;
    unsigned pkw[8];                    // P_{kt,h}: keys kt*16+g*4+{2h,2h+1}
    #pragma unroll
    for (int kt = 0; kt < 4; ++kt) {
      const float e0 = exp2f(s[kt][0] - m_run), e1 = exp2f(s[kt][1] - m_run);
      const float e2 = exp2f(s[kt][2] - m_run), e3 = exp2f(s[kt][3] - m_run);
      lsum += (e0 + e1) + (e2 + e3);
      pkw[kt * 2 + 0] = cvt_pk_bf16(e0, e1);
      pkw[kt * 2 + 1] = cvt_pk_bf16(e2, e3);
    }
    lsum += __shfl_xor(lsum, 16);
    lsum += __shfl_xor(lsum, 32);
    l_run += lsum;

    // ---- O^T += V^T . P^T : lane-local P; V = ONE b128 per slice ----
    // slice kk slot j -> key 32kk + 16(j>>2) + 4g + (j&3); V row-byte
    // 64kk + 16g + 2j matches exactly (key-permuted layout).
    u32x4 pw0 = {pkw[0], pkw[1], pkw[2], pkw[3]};
    u32x4 pw1 = {pkw[4], pkw[5], pkw[6], pkw[7]};
    const u16x8 pf0 = __builtin_bit_cast(u16x8, pw0);   // keys 0..31 (remapped)
    const u16x8 pf1 = __builtin_bit_cast(u16x8, pw1);   // keys 32..63 (remapped)
    __builtin_amdgcn_s_setprio(1);
    #pragma unroll
    for (int dt = 0; dt < 8; ++dt) {
      const char* vp = vbb + (dt * 16 + lq) * 128;       // ch = dt*16 + lq
      u16x8 vf0 = *(const u16x8*)(vp + ((g * 16) ^ swzVl));
      oacc[dt] = mfma16(vf0, pf0, oacc[dt]);
      u16x8 vf1 = *(const u16x8*)(vp + ((64 + g * 16) ^ swzVl));
      oacc[dt] = mfma16(vf1, pf1, oacc[dt]);
    }
    __builtin_amdgcn_s_setprio(0);
    asm volatile("s_waitcnt lgkmcnt(0)" ::: "memory"); // all reads of buf done
    __builtin_amdgcn_s_barrier();                      // safe to overwrite other buf
  }
  #undef STAGE

  // ---- epilogue: normalized bf16 partials, channel-major + (m,l) ----
  const float rinv = 1.0f / l_run;
  const int n = q0w + lq;
  unsigned short* po = PO + (size_t)sp * (BB * CC * NN) + (size_t)b * (CC * NN);
  #pragma unroll
  for (int dt = 0; dt < 8; ++dt) {
    #pragma unroll
    for (int r = 0; r < 4; ++r) {
      const int c = dt * 16 + g * 4 + r;
      po[(size_t)c * NN + n] = f2bf(oacc[dt][r] * rinv);
    }
  }
  if (g == 0) PML[((size_t)sp * BB + b) * NN + n] = float2{m_run, l_run};
}

// ---------------------------------------------------------------------------
// Kernel 3: combine 2 bf16 normalized partials + residual.
// out = x + w0*o0 + w1*o1,  w_s = l_s*exp2(m_s-M)/(sum)   (R6 math, proven)
// ---------------------------------------------------------------------------
__global__ __launch_bounds__(256) void combine(
    const float* __restrict__ x,
    const unsigned short* __restrict__ PO,
    const float2* __restrict__ PML,
    float* __restrict__ out)
{
  const size_t base = ((size_t)blockIdx.x * 256 + threadIdx.x) * 4;
  const int n = (int)(base & 4095);
  const int b = (int)(base >> 19);            // base = ((b*128+c)*4096)+n
  const float2 ml0 = PML[(size_t)b * NN + n];
  const float2 ml1 = PML[(size_t)(BB + b) * NN + n];
  const float M = fmaxf(ml0.x, ml1.x);
  float w0 = ml0.y * exp2f(ml0.x - M);
  float w1 = ml1.y * exp2f(ml1.x - M);
  const float inv = 1.0f / (w0 + w1);
  w0 *= inv; w1 *= inv;

  ushort4 o0 = *(const ushort4*)(PO + base);
  ushort4 o1 = *(const ushort4*)(PO + (size_t)BB * CC * NN + base);
  float4 xv = *(const float4*)(x + base);
  float4 r;
  r.x = xv.x + w0 * bf2f(o0.x) + w1 * bf2f(o1.x);
  r.y = xv.y + w0 * bf2f(o0.y) + w1 * bf2f(o1.y);
  r.z = xv.z + w0 * bf2f(o0.z) + w1 * bf2f(o1.z);
  r.w = xv.w + w0 * bf2f(o0.w) + w1 * bf2f(o1.w);
  *(float4*)(out + base) = r;
}

extern "C" void kernel_launch(void* const* d_in, const int* in_sizes, int n_in,
                              void* d_out, int out_size, void* d_ws, size_t ws_size,
                              hipStream_t stream) {
  (void)in_sizes; (void)n_in; (void)out_size; (void)ws_size;
  const float* x  = (const float*)d_in[0];
  const float* Wq = (const float*)d_in[1];
  const float* bq = (const float*)d_in[2];
  const float* Wk = (const float*)d_in[3];
  const float* bk = (const float*)d_in[4];
  const float* Wv = (const float*)d_in[5];
  const float* bv = (const float*)d_in[6];

  unsigned short* Q   = (unsigned short*)d_ws;                  // 8 MB
  unsigned short* K   = Q + (size_t)BB * NN * CC;               // 8 MB
  unsigned short* V   = K + (size_t)BB * NN * CC;               // 8 MB
  unsigned short* PO  = V + (size_t)BB * NN * CC;               // 16 MB (2 bf16 partials)
  float2* PML         = (float2*)(PO + (size_t)2 * BB * CC * NN); // 512 KB
  unsigned short* Qwb = (unsigned short*)(PML + (size_t)2 * BB * NN); // 32 KB
  unsigned short* Vwb = Qwb + (size_t)CC * CC;                  // 32 KB
  float* csk = (float*)(Vwb + (size_t)CC * CC);                 // 512 B
  float* out = (float*)d_out;

  prep<<<dim3(65), dim3(256), 0, stream>>>(Wq, Wv, Wk, Qwb, Vwb, csk);
  qkv_proj<<<dim3(BB * (NN / 64)), dim3(256), 0, stream>>>(x, Qwb, bq, csk, bk, Vwb, bv, Q, K, V);
  flash_attn<<<dim3(BB * 32 * 2), dim3(512), 0, stream>>>(Q, K, V, PO, PML);
  combine<<<dim3((BB * CC * NN) / (256 * 4)), dim3(256), 0, stream>>>(x, PO, PML, out);
}

// Round 14
// 138.995 us; speedup vs baseline: 1.8261x; 1.0012x over previous
//
#include <hip/hip_runtime.h>

#define BB 8
#define CC 128
#define NN 4096   // H*W = 64*64

typedef __bf16 bf16x8_t __attribute__((ext_vector_type(8)));
typedef unsigned short u16x8 __attribute__((ext_vector_type(8)));
typedef float f32x4 __attribute__((ext_vector_type(4)));
typedef unsigned int u32x4 __attribute__((ext_vector_type(4)));
typedef __attribute__((address_space(1))) const unsigned int gu32;
typedef __attribute__((address_space(3))) unsigned int lu32;

#define KSCALE 0.12753262456033348f   // (1/sqrt(128)) * log2(e)

__device__ __forceinline__ unsigned short f2bf(float f) {
  unsigned int u = __builtin_bit_cast(unsigned int, f);
  u += 0x7fffu + ((u >> 16) & 1u);          // RNE
  return (unsigned short)(u >> 16);
}

__device__ __forceinline__ float bf2f(unsigned short s) {
  unsigned int u = ((unsigned int)s) << 16;
  return __builtin_bit_cast(float, u);
}

__device__ __forceinline__ unsigned int cvt_pk_bf16(float lo, float hi) {
  unsigned int r;
  asm("v_cvt_pk_bf16_f32 %0, %1, %2" : "=v"(r) : "v"(lo), "v"(hi));
  return r;
}

__device__ __forceinline__ f32x4 mfma16(u16x8 a, u16x8 b, f32x4 c) {
  return __builtin_amdgcn_mfma_f32_16x16x32_bf16(
      __builtin_bit_cast(bf16x8_t, a), __builtin_bit_cast(bf16x8_t, b), c, 0, 0, 0);
}

// ---------------------------------------------------------------------------
// Kernel 0: prep.  Blocks 0..63: Wq*KSCALE, Wv -> bf16.  Block 64: csk[c]=sum_o Wk[o][c]
// ---------------------------------------------------------------------------
__global__ void prep(const float* __restrict__ Wq, const float* __restrict__ Wv,
                     const float* __restrict__ Wk,
                     unsigned short* __restrict__ Qwb, unsigned short* __restrict__ Vwb,
                     float* __restrict__ csk) {
  if (blockIdx.x < 64) {
    const int i = blockIdx.x * 256 + threadIdx.x;
    Qwb[i] = f2bf(Wq[i] * KSCALE);
    Vwb[i] = f2bf(Wv[i]);
  } else if (threadIdx.x < CC) {
    const int c = threadIdx.x;
    float s = 0.f;
    for (int o = 0; o < CC; ++o) s += Wk[(size_t)o * CC + c];
    csk[c] = s;
  }
}

// ---------------------------------------------------------------------------
// Kernel 1: QKV projection (proven).
//  Q[b][n][o] = (x.Wq^T + bq) * KSCALE   bf16 pixel-major
//  K[b][n][c] =  x[c][n]*csk[c] + bk[c]  bf16 pixel-major
//  V[b][o][n] =  x.Wv^T + bv             bf16 channel-major
// ---------------------------------------------------------------------------
__global__ __launch_bounds__(256, 2) void qkv_proj(
    const float* __restrict__ x,
    const unsigned short* __restrict__ Qwb, const float* __restrict__ bq,
    const float* __restrict__ csk, const float* __restrict__ bk,
    const unsigned short* __restrict__ Vwb, const float* __restrict__ bv,
    unsigned short* __restrict__ Q,
    unsigned short* __restrict__ K,
    unsigned short* __restrict__ V)
{
  const int b  = blockIdx.x & 7;
  const int n0 = (blockIdx.x >> 3) << 6;
  const int t  = threadIdx.x;
  const int lane = t & 63;
  const int w  = t >> 6;
  const int lq = lane & 15;
  const int g  = lane >> 4;

  __shared__ unsigned short xs[64][136];
  __shared__ unsigned short ks[64][136];
  __shared__ unsigned short vs[128][72];

  {
    const int n = t & 63;
    const float* xp = x + (size_t)b * (CC * NN) + n0 + n;
    for (int c = t >> 6; c < CC; c += 4) {
      const float xv = xp[(size_t)c * NN];
      xs[n][c] = f2bf(xv);
      ks[n][c] = f2bf(xv * csk[c] + bk[c]);
    }
  }
  __syncthreads();

  u16x8 a[4];
  {
    const unsigned short* ap = &xs[w * 16 + lq][g * 8];
    for (int ksl = 0; ksl < 4; ++ksl) a[ksl] = *(const u16x8*)(ap + ksl * 32);
  }

  for (int ot = 0; ot < 8; ++ot) {
    f32x4 aq = {0.f,0.f,0.f,0.f}, av = {0.f,0.f,0.f,0.f};
    const int o = ot * 16 + lq;
    const unsigned short* wq = Qwb + (size_t)o * CC + g * 8;
    const unsigned short* wv = Vwb + (size_t)o * CC + g * 8;
    for (int ksl = 0; ksl < 4; ++ksl) {
      aq = mfma16(a[ksl], *(const u16x8*)(wq + ksl * 32), aq);
      av = mfma16(a[ksl], *(const u16x8*)(wv + ksl * 32), av);
    }
    const float bqv = bq[o] * KSCALE, bvv = bv[o];
    for (int r = 0; r < 4; ++r) {
      const int nl = w * 16 + g * 4 + r;
      Q[((size_t)b * NN + n0 + nl) * CC + o] = f2bf(aq[r] + bqv);
      vs[o][nl] = f2bf(av[r] + bvv);
    }
  }
  __syncthreads();

  {
    unsigned short* kout = K + ((size_t)b * NN + n0) * CC;
    for (int i = t; i < 64 * 16; i += 256) {
      const int n = i >> 4, oc = (i & 15) * 8;
      *(uint4*)(kout + (size_t)n * CC + oc) = *(const uint4*)&ks[n][oc];
    }
  }
  {
    unsigned short* vout = V + (size_t)b * (CC * NN) + n0;
    for (int i = t; i < 128 * 32; i += 256) {
      const int c  = i >> 5;
      const int np = (i & 31) << 1;
      *(unsigned int*)(vout + (size_t)c * NN + np) = *(const unsigned int*)&vs[c][np];
    }
  }
}

// ---------------------------------------------------------------------------
// Kernel 2: flash attention partials, KV split 2-way (R11 structure verbatim:
// FETCH ~12MB, 0 bank conflicts, 2-barrier loop, vmcnt(10)).
// Changes vs R11: (a) bf16 NORMALIZED partials (halves partial write bytes;
// accuracy proven in R6-R8), (b) v_max3-friendly row-max nesting (T17).
// R12's cross-tile pipeline REJECTED (scratch spill + L2 thrash, -100% perf).
// ---------------------------------------------------------------------------
__global__ __launch_bounds__(512, 4) void flash_attn(
    const unsigned short* __restrict__ Q,
    const unsigned short* __restrict__ K,
    const unsigned short* __restrict__ V,
    unsigned short* __restrict__ PO,     // [2][B][C][N] bf16 normalized partials
    float2* __restrict__ PML)            // [2][B][N]
{
  const int bid = blockIdx.x;
  const int b  = bid & 7;                    // batch -> XCD-local K/V/Q
  const int qb = (bid >> 3) & 31;
  const int sp = bid >> 8;                   // KV half 0/1
  const int kv0 = sp << 11;                  // 2048 keys per half
  const int t  = threadIdx.x;
  const int lane = t & 63;
  const int w  = t >> 6;                     // wave 0..7
  const int lq = lane & 15;
  const int g  = lane >> 4;
  const int q0w = (qb << 7) + (w << 4);      // 16 q-rows per wave

  __shared__ unsigned short KtL[2][64 * 128];   // 16KB each: [key][c], swizzled
  __shared__ unsigned short VlL[2][128 * 64];   // 16KB each: [ch][64keys permuted]

  // Q fragments (B-operand of swapped QK^T): col q = lq
  u16x8 qf[4];
  {
    const unsigned short* qp = Q + ((size_t)b * NN + q0w + lq) * CC + g * 8;
    #pragma unroll
    for (int ksl = 0; ksl < 4; ++ksl) qf[ksl] = *(const u16x8*)(qp + ksl * 32);
  }

  // ---- staging offsets (pre-inverse-swizzled source, linear LDS dest) ----
  const char* kgb = (const char*)(K + (size_t)b * NN * CC);   // 256B key rows
  const char* vgb = (const char*)(V + (size_t)b * CC * NN);   // 8192B channel rows
  int soK[2];
  #pragma unroll
  for (int j = 0; j < 2; ++j) {
    const int p = t * 16 + j * 8192;
    const int row = p >> 8;                    // 0..63
    soK[j] = (p & ~255) | ((p & 255) ^ ((row & 15) << 4));
  }
  // V: 8 chunks of 4B per thread. Physical LDS byte p -> channel ch=p>>7,
  // logical L = (p&127) ^ ((ch&7)<<4), global row-byte gb(L):
  //   L bits: b6=kk b5:4=g b3=h b2:1=r b0=parity -> gb = kk<<6|h<<5|g<<3|r<<1|par
  int vOff[8];
  #pragma unroll
  for (int n = 0; n < 8; ++n) {
    const int p = t * 4 + n * 2048;
    const int ch = p >> 7;
    const int L = (p & 127) ^ ((ch & 7) << 4);
    const int gb = (L & 7) | (((L >> 4) & 3) << 3) | (((L >> 3) & 1) << 5) | ((L >> 6) << 6);
    vOff[n] = ch * (NN * 2) + gb;
  }

  #define STAGE(nb, kv) do {                                                      \
    const char* kg_ = kgb + ((size_t)(kv) << 8);                                  \
    const char* vg_ = vgb + ((size_t)(kv) << 1);                                  \
    _Pragma("unroll")                                                             \
    for (int j = 0; j < 2; ++j)                                                   \
      __builtin_amdgcn_global_load_lds((gu32*)(kg_ + soK[j]),                     \
          (lu32*)((char*)KtL + (nb) * 16384 + t * 16 + j * 8192), 16, 0, 0);      \
    _Pragma("unroll")                                                             \
    for (int n = 0; n < 8; ++n)                                                   \
      __builtin_amdgcn_global_load_lds((gu32*)(vg_ + vOff[n]),                    \
          (lu32*)((char*)VlL + (nb) * 16384 + t * 4 + n * 2048), 4, 0, 0);        \
  } while (0)

  f32x4 oacc[8];
  #pragma unroll
  for (int i = 0; i < 8; ++i) oacc[i] = f32x4{0.f, 0.f, 0.f, 0.f};
  float m_run = -1e30f, l_run = 0.f;

  const int swzK  = lq << 4;                   // K read swizzle: row&15 = lq
  const int swzVl = (lq & 7) << 4;             // V read swizzle: ch&7 = lq&7

  STAGE(0, kv0);

  for (int tt = 0; tt < 32; ++tt) {
    const int cur = tt & 1;
    if (tt < 31) {
      STAGE(cur ^ 1, kv0 + (tt + 1) * 64);
      asm volatile("s_waitcnt vmcnt(10)" ::: "memory");  // current tile resident
    } else {
      asm volatile("s_waitcnt vmcnt(0)" ::: "memory");
    }
    __builtin_amdgcn_s_barrier();

    const char* kb  = (const char*)KtL + cur * 16384;
    const char* vbb = (const char*)VlL + cur * 16384;

    // ---- S^T = K . Q^T  (row = key, col = q) ----
    f32x4 s[4];
    #pragma unroll
    for (int kt = 0; kt < 4; ++kt) s[kt] = f32x4{0.f, 0.f, 0.f, 0.f};
    __builtin_amdgcn_s_setprio(1);
    #pragma unroll
    for (int kt = 0; kt < 4; ++kt) {
      const char* kp = kb + (kt * 16 + lq) * 256;
      #pragma unroll
      for (int ksl = 0; ksl < 4; ++ksl) {
        u16x8 kf = *(const u16x8*)(kp + ((ksl * 64 + g * 16) ^ swzK));
        s[kt] = mfma16(kf, qf[ksl], s[kt]);
      }
    }
    __builtin_amdgcn_s_setprio(0);

    // ---- online softmax (per q column; defer-max T13; v_max3 tree T17) ----
    // 16 values via 3-input groups -> v_max3_f32
    float pa = fmaxf(fmaxf(s[0][0], s[0][1]), s[0][2]);
    float pb = fmaxf(fmaxf(s[0][3], s[1][0]), s[1][1]);
    float pc = fmaxf(fmaxf(s[1][2], s[1][3]), s[2][0]);
    float pd = fmaxf(fmaxf(s[2][1], s[2][2]), s[2][3]);
    float pe = fmaxf(fmaxf(s[3][0], s[3][1]), s[3][2]);
    float pm = fmaxf(fmaxf(pa, pb), pc);
    pm = fmaxf(fmaxf(pm, pd), fmaxf(pe, s[3][3]));
    pm = fmaxf(pm, __shfl_xor(pm, 16));
    pm = fmaxf(pm, __shfl_xor(pm, 32));
    if (!__all(pm - m_run <= 8.0f)) {
      const float m_new = fmaxf(m_run, pm);
      const float alpha = exp2f(m_run - m_new);
      l_run *= alpha;
      #pragma unroll
      for (int i = 0; i < 8; ++i) {
        oacc[i][0] *= alpha; oacc[i][1] *= alpha;
        oacc[i][2] *= alpha; oacc[i][3] *= alpha;
      }
      m_run = m_new;
    }
    float lsum = 0.f;
    unsigned pkw[8];                    // P_{kt,h}: keys kt*16+g*4+{2h,2h+1}
    #pragma unroll
    for (int kt = 0; kt < 4; ++kt) {
      const float e0 = exp2f(s[kt][0] - m_run), e1 = exp2f(s[kt][1] - m_run);
      const float e2 = exp2f(s[kt][2] - m_run), e3 = exp2f(s[kt][3] - m_run);
      lsum += (e0 + e1) + (e2 + e3);
      pkw[kt * 2 + 0] = cvt_pk_bf16(e0, e1);
      pkw[kt * 2 + 1] = cvt_pk_bf16(e2, e3);
    }
    lsum += __shfl_xor(lsum, 16);
    lsum += __shfl_xor(lsum, 32);
    l_run += lsum;

    // ---- O^T += V^T . P^T : lane-local P; V = ONE b128 per slice ----
    // slice kk slot j -> key 32kk + 16(j>>2) + 4g + (j&3); V row-byte
    // 64kk + 16g + 2j matches exactly (key-permuted layout).
    u32x4 pw0 = {pkw[0], pkw[1], pkw[2], pkw[3]};
    u32x4 pw1 = {pkw[4], pkw[5], pkw[6], pkw[7]};
    const u16x8 pf0 = __builtin_bit_cast(u16x8, pw0);   // keys 0..31 (remapped)
    const u16x8 pf1 = __builtin_bit_cast(u16x8, pw1);   // keys 32..63 (remapped)
    __builtin_amdgcn_s_setprio(1);
    #pragma unroll
    for (int dt = 0; dt < 8; ++dt) {
      const char* vp = vbb + (dt * 16 + lq) * 128;       // ch = dt*16 + lq
      u16x8 vf0 = *(const u16x8*)(vp + ((g * 16) ^ swzVl));
      oacc[dt] = mfma16(vf0, pf0, oacc[dt]);
      u16x8 vf1 = *(const u16x8*)(vp + ((64 + g * 16) ^ swzVl));
      oacc[dt] = mfma16(vf1, pf1, oacc[dt]);
    }
    __builtin_amdgcn_s_setprio(0);
    asm volatile("s_waitcnt lgkmcnt(0)" ::: "memory"); // all reads of buf done
    __builtin_amdgcn_s_barrier();                      // safe to overwrite other buf
  }
  #undef STAGE

  // ---- epilogue: normalized bf16 partials, channel-major + (m,l) ----
  const float rinv = 1.0f / l_run;
  const int n = q0w + lq;
  unsigned short* po = PO + (size_t)sp * (BB * CC * NN) + (size_t)b * (CC * NN);
  #pragma unroll
  for (int dt = 0; dt < 8; ++dt) {
    #pragma unroll
    for (int r = 0; r < 4; ++r) {
      const int c = dt * 16 + g * 4 + r;
      po[(size_t)c * NN + n] = f2bf(oacc[dt][r] * rinv);
    }
  }
  if (g == 0) PML[((size_t)sp * BB + b) * NN + n] = float2{m_run, l_run};
}

// ---------------------------------------------------------------------------
// Kernel 3: combine 2 bf16 normalized partials + residual.
// out = x + w0*o0 + w1*o1,  w_s = l_s*exp2(m_s-M)/(sum)   (R6 math, proven)
// ---------------------------------------------------------------------------
__global__ __launch_bounds__(256) void combine(
    const float* __restrict__ x,
    const unsigned short* __restrict__ PO,
    const float2* __restrict__ PML,
    float* __restrict__ out)
{
  const size_t base = ((size_t)blockIdx.x * 256 + threadIdx.x) * 4;
  const int n = (int)(base & 4095);
  const int b = (int)(base >> 19);            // base = ((b*128+c)*4096)+n
  const float2 ml0 = PML[(size_t)b * NN + n];
  const float2 ml1 = PML[(size_t)(BB + b) * NN + n];
  const float M = fmaxf(ml0.x, ml1.x);
  float w0 = ml0.y * exp2f(ml0.x - M);
  float w1 = ml1.y * exp2f(ml1.x - M);
  const float inv = 1.0f / (w0 + w1);
  w0 *= inv; w1 *= inv;

  ushort4 o0 = *(const ushort4*)(PO + base);
  ushort4 o1 = *(const ushort4*)(PO + (size_t)BB * CC * NN + base);
  float4 xv = *(const float4*)(x + base);
  float4 r;
  r.x = xv.x + w0 * bf2f(o0.x) + w1 * bf2f(o1.x);
  r.y = xv.y + w0 * bf2f(o0.y) + w1 * bf2f(o1.y);
  r.z = xv.z + w0 * bf2f(o0.z) + w1 * bf2f(o1.z);
  r.w = xv.w + w0 * bf2f(o0.w) + w1 * bf2f(o1.w);
  *(float4*)(out + base) = r;
}

extern "C" void kernel_launch(void* const* d_in, const int* in_sizes, int n_in,
                              void* d_out, int out_size, void* d_ws, size_t ws_size,
                              hipStream_t stream) {
  (void)in_sizes; (void)n_in; (void)out_size; (void)ws_size;
  const float* x  = (const float*)d_in[0];
  const float* Wq = (const float*)d_in[1];
  const float* bq = (const float*)d_in[2];
  const float* Wk = (const float*)d_in[3];
  const float* bk = (const float*)d_in[4];
  const float* Wv = (const float*)d_in[5];
  const float* bv = (const float*)d_in[6];

  unsigned short* Q   = (unsigned short*)d_ws;                  // 8 MB
  unsigned short* K   = Q + (size_t)BB * NN * CC;               // 8 MB
  unsigned short* V   = K + (size_t)BB * NN * CC;               // 8 MB
  unsigned short* PO  = V + (size_t)BB * NN * CC;               // 16 MB (2 bf16 partials)
  float2* PML         = (float2*)(PO + (size_t)2 * BB * CC * NN); // 512 KB
  unsigned short* Qwb = (unsigned short*)(PML + (size_t)2 * BB * NN); // 32 KB
  unsigned short* Vwb = Qwb + (size_t)CC * CC;                  // 32 KB
  float* csk = (float*)(Vwb + (size_t)CC * CC);                 // 512 B
  float* out = (float*)d_out;

  prep<<<dim3(65), dim3(256), 0, stream>>>(Wq, Wv, Wk, Qwb, Vwb, csk);
  qkv_proj<<<dim3(BB * (NN / 64)), dim3(256), 0, stream>>>(x, Qwb, bq, csk, bk, Vwb, bv, Q, K, V);
  flash_attn<<<dim3(BB * 32 * 2), dim3(512), 0, stream>>>(Q, K, V, PO, PML);
  combine<<<dim3((BB * CC * NN) / (256 * 4)), dim3(256), 0, stream>>>(x, PO, PML, out);
}